// Round 22
// baseline (42.190 us; speedup 1.0000x reference)
//
#include <hip/hip_runtime.h>
#include <hip/hip_bf16.h>
#include <math.h>

// Problem constants
#define Bn 8
#define Cn 64
#define Hn 128
#define Wn 128
#define Rn 4

typedef __bf16 v8bf __attribute__((ext_vector_type(8)));
typedef float  v16f __attribute__((ext_vector_type(16)));

__device__ __forceinline__ float leaky(float x) { return x >= 0.f ? x : 0.1f * x; }

__device__ __forceinline__ unsigned bf16pair(float a, float b) {
    __hip_bfloat16 ha = __float2bfloat16(a);
    __hip_bfloat16 hb = __float2bfloat16(b);
    return (unsigned)*reinterpret_cast<unsigned short*>(&ha) |
           ((unsigned)*reinterpret_cast<unsigned short*>(&hb) << 16);
}

// VALU wave-wide shifts via DPP (no DS pipe). bound_ctrl -> out-of-range = 0,
// which matches the image border semantics at lanes 0 / 63 exactly.
__device__ __forceinline__ float dpp_up1(float x) {    // lane n <- lane n-1; lane0 = 0
    int r = __builtin_amdgcn_update_dpp(0, __builtin_bit_cast(int, x),
                                        0x138 /*wave_shr:1*/, 0xf, 0xf, true);
    return __builtin_bit_cast(float, r);
}
__device__ __forceinline__ float dpp_down1(float x) {  // lane n <- lane n+1; lane63 = 0
    int r = __builtin_amdgcn_update_dpp(0, __builtin_bit_cast(int, x),
                                        0x130 /*wave_shl:1*/, 0xf, 0xf, true);
    return __builtin_bit_cast(float, r);
}

// ---------------------------------------------------------------------------
// Kernel A: per-batch dynamic depthwise kernels + channel attn; block Bn
// converts w_conv -> bf16 [o][c].
//   kern_g[b][c][r][12]  (b*3072 + c*48 + r*12 + kk; slots 9..11 pad)
//   att_g [b][r][c]
// ---------------------------------------------------------------------------
__global__ __launch_bounds__(256) void precomp_kernel(
    const float* __restrict__ deg, const float* __restrict__ w_k1,
    const float* __restrict__ w_k2, const float* __restrict__ w_ca1,
    const float* __restrict__ w_ca2, const float* __restrict__ w_conv,
    float* __restrict__ kern_g, float* __restrict__ att_g,
    unsigned short* __restrict__ wbf)
{
    const int tid = threadIdx.x;
    if (blockIdx.x == Bn) {                       // w_conv -> bf16
        for (int f = tid; f < Cn * Cn; f += 256) {
            __hip_bfloat16 hx = __float2bfloat16(w_conv[f]);
            wbf[f] = *reinterpret_cast<unsigned short*>(&hx);
        }
        return;
    }
    const int b = blockIdx.x;
    __shared__ float y_s[64], a_s[64];
    if (tid < 64) {
        float sy = 0.f, sa = 0.f;
#pragma unroll 8
        for (int j = 0; j < 64; ++j) {
            float d = deg[b * 64 + j];
            sy += d * w_k1[tid * 64 + j];
            sa += d * w_ca1[tid * 64 + j];
        }
        y_s[tid] = leaky(sy);
        a_s[tid] = leaky(sa);
    }
    __syncthreads();
    for (int f = tid; f < Cn * Rn * 9; f += 256) {
        int c = f / 36;
        int j = f - c * 36;
        int r = j / 9;
        int kk = j - r * 9;
        int o = c * 9 + kk;
        const float* wp = &w_k2[(r * 576 + o) * 16];
        const float* yp = &y_s[r * 16];
        float s = 0.f;
#pragma unroll
        for (int i = 0; i < 16; ++i) s += yp[i] * wp[i];
        kern_g[b * 3072 + c * 48 + r * 12 + kk] = s;
    }
    {
        int r = tid >> 6, o = tid & 63;
        const float* wp = &w_ca2[(r * 64 + o) * 16];
        const float* ap = &a_s[r * 16];
        float s = 0.f;
#pragma unroll
        for (int i = 0; i < 16; ++i) s += ap[i] * wp[i];
        att_g[b * 256 + tid] = 1.f / (1.f + expf(-s));
    }
}

// ---------------------------------------------------------------------------
// Main kernel: one block per (b,h) row, 512 threads = 8 waves, 2 barriers.
// R20 (col-pair + DPP + 2-deep pipeline) with the t_lds write path changed
// to the R11-verified ws-permuted subtile layout: col0 -> row lane, col1 ->
// row 64+lane, one contiguous ds_write_b128 each (conflict-free minimum).
// Phase-2 Bf read at ws = (wn>>1)|((wn&1)<<6) (R11-verified addressing).
// ---------------------------------------------------------------------------
__global__ __launch_bounds__(512) void da_main(
    const float* __restrict__ x0, const float* __restrict__ q_map,
    const unsigned short* __restrict__ wbf, const float* __restrict__ b_conv,
    const float* __restrict__ w_g1, const float* __restrict__ b_g1,
    const float* __restrict__ w_g2, const float* __restrict__ b_g2,
    const float* __restrict__ kern_g, const float* __restrict__ att_g,
    float* __restrict__ out)
{
    __shared__ __align__(16) float kern_lds[Cn * 48];           // 12 KB
    __shared__ __align__(16) unsigned short wc_lds[8][Cn][8];   // 8 KB
    __shared__ __align__(16) unsigned short t_lds[8][130][8];   // 16.6 KB (ws-permuted)
    __shared__ float att_lds[Rn * 68];                          // 1.1 KB
    __shared__ float bias_lds[Cn];                              // 0.25 KB
    __shared__ unsigned ridx[Wn];                               // 0.5 KB  r1 | r2<<16

    const int tid = threadIdx.x;
    const int ob = blockIdx.x;
    // XCD-aware swizzle: XCD i gets batch i (4 MB image == one L2).
    const int sb = ((ob & 7) << 7) | (ob >> 3);
    const int b = sb >> 7;
    const int h = sb & 127;

    const int lane = tid & 63;
    const int g = tid >> 6;               // wave id: channels [8g, 8g+8)
    const int w0 = 2 * lane;              // this lane's column pair
    const int w1 = w0 + 1;

    // ---- phase 0: staging (R12-identical) ----
    for (int f = tid; f < Cn * 48; f += 512)
        kern_lds[f] = kern_g[b * 3072 + f];
    {   // wc subtiles: one conflict-free b128 write per thread
        int cq = tid & 7, o = tid >> 3;
        *(v8bf*)&wc_lds[cq][o][0] = *(const v8bf*)&wbf[o * 64 + cq * 8];
    }
    if (tid < 256) att_lds[(tid >> 6) * 68 + (tid & 63)] = att_g[b * 256 + tid];
    if (tid < 64) bias_lds[tid] = b_conv[tid];

    // routing: once per column, published packed (r1 | r2<<16)
    if (tid < 128) {
        const int wc = tid;
        float qv[9];
#pragma unroll
        for (int dh = 0; dh < 3; ++dh) {
            int row = h - 1 + dh;
#pragma unroll
            for (int dw = 0; dw < 3; ++dw) {
                int col = wc - 1 + dw;
                qv[dh * 3 + dw] = (row >= 0 && row < Hn && col >= 0 && col < Wn)
                                      ? q_map[(b * Hn + row) * Wn + col] : 0.f;
            }
        }
        float best1 = -1e30f, best2 = -1e30f;
        int r1 = 0, r2 = 0;
#pragma unroll
        for (int r = 0; r < Rn; ++r) {
            float s1 = b_g1[r], s2 = b_g2[r];
#pragma unroll
            for (int k = 0; k < 9; ++k) {
                s1 += qv[k] * w_g1[r * 9 + k];
                s2 += qv[k] * w_g2[r * 9 + k];
            }
            if (s1 > best1) { best1 = s1; r1 = r; }   // strict > == first argmax
            if (s2 > best2) { best2 = s2; r2 = r; }
        }
        ridx[wc] = (unsigned)r1 | ((unsigned)r2 << 16);
    }
    __syncthreads();

    // ---- phase 1: column-pair depthwise, 2-deep pipelined, DPP exchange ----
    const bool okm = (h > 0);
    const bool okp = (h < Hn - 1);
    const float* xbase = x0 + (size_t)(b * Cn) * Hn * Wn + h * Wn + w0;
    const int r1a = (int)(ridx[w0] & 0xffffu);
    const int r1b = (int)(ridx[w1] & 0xffffu);

    // two named prefetch buffers (3 x float2 each)
    float2 b0m, b00, b0p;                 // buffer 0
    float2 b1m, b10, b1p;                 // buffer 1

#define LOADC(CI, BM, B0, BP)                                             \
    do {                                                                  \
        const float* xc = xbase + (8 * g + (CI)) * (Hn * Wn);             \
        BM = okm ? *(const float2*)(xc - Wn) : make_float2(0.f, 0.f);     \
        B0 = *(const float2*)xc;                                          \
        BP = okp ? *(const float2*)(xc + Wn) : make_float2(0.f, 0.f);     \
    } while (0)

    uint4 pk0, pk1;                       // 8-channel bf16 packs per column
    float tp0 = 0.f, tp1 = 0.f;           // previous channel's outputs
    LOADC(0, b0m, b00, b0p);
    LOADC(1, b1m, b10, b1p);
#pragma unroll
    for (int ci = 0; ci < 8; ++ci) {
        float2 avm, av0, avp;
        if ((ci & 1) == 0) { avm = b0m; av0 = b00; avp = b0p; }
        else               { avm = b1m; av0 = b10; avp = b1p; }
        if (ci < 6) {                      // refill the freed buffer (static)
            if ((ci & 1) == 0) LOADC(ci + 2, b0m, b00, b0p);
            else               LOADC(ci + 2, b1m, b10, b1p);
        }

        // outer neighbors via VALU DPP wave shifts (lane0/63 auto-zero = border)
        float lm = dpp_up1(avm.y),  l0 = dpp_up1(av0.y),  lp = dpp_up1(avp.y);
        float rm = dpp_down1(avm.x), r0 = dpp_down1(av0.x), rp = dpp_down1(avp.x);

        const int c = 8 * g + ci;
        const float* kpa = &kern_lds[c * 48 + r1a * 12];    // col0 kernel
        float4 a03 = *(const float4*)kpa;
        float4 a47 = *(const float4*)(kpa + 4);
        float a8 = kpa[8];
        float t0 = lm    * a03.x + avm.x * a03.y + avm.y * a03.z
                 + l0    * a03.w + av0.x * a47.x + av0.y * a47.y
                 + lp    * a47.z + avp.x * a47.w + avp.y * a8;
        const float* kpb = &kern_lds[c * 48 + r1b * 12];    // col1 kernel
        float4 b03 = *(const float4*)kpb;
        float4 b47 = *(const float4*)(kpb + 4);
        float b8 = kpb[8];
        float t1 = avm.x * b03.x + avm.y * b03.y + rm    * b03.z
                 + av0.x * b03.w + av0.y * b47.x + r0    * b47.y
                 + avp.x * b47.z + avp.y * b47.w + rp    * b8;
        t0 = leaky(t0);
        t1 = leaky(t1);

        if (ci & 1) {                     // pack the completed channel pair
            const unsigned q0 = bf16pair(tp0, t0);
            const unsigned q1 = bf16pair(tp1, t1);
            const int slot = ci >> 1;     // 0..3, static after unroll
            if (slot == 0)      { pk0.x = q0; pk1.x = q1; }
            else if (slot == 1) { pk0.y = q0; pk1.y = q1; }
            else if (slot == 2) { pk0.z = q0; pk1.z = q1; }
            else                { pk0.w = q0; pk1.w = q1; }
        } else {
            tp0 = t0;
            tp1 = t1;
        }
    }
#undef LOADC
    // contiguous conflict-free b128 writes (R11-verified layout):
    // col0 (even w) -> row lane, col1 (odd w) -> row 64+lane
    *(uint4*)&t_lds[g][lane][0] = pk0;
    *(uint4*)&t_lds[g][64 + lane][0] = pk1;
    __syncthreads();

    // ---- phase 2: MFMA channel mix + fused epilogue (R11 read addressing) ----
    const int v = tid >> 6;               // wave 0..7
    const int wt = v & 3;                 // w-tile (32 cols)
    const int oh = v >> 2;                // o-half (32 rows)
    const int col = lane & 31;
    const int kh = lane >> 5;
    const int wn = wt * 32 + col;         // this lane's output column
    const int ws = (wn >> 1) | ((wn & 1) << 6);   // permuted t_lds row

    v8bf Bf[4];
#pragma unroll
    for (int ks = 0; ks < 4; ++ks)
        Bf[ks] = *(const v8bf*)&t_lds[2 * ks + kh][ws][0];

    v16f acc;
#pragma unroll
    for (int i = 0; i < 16; ++i) acc[i] = 0.f;

#pragma unroll
    for (int ks = 0; ks < 4; ++ks) {
        const int cq = 2 * ks + kh;
        v8bf Af = *(const v8bf*)&wc_lds[cq][oh * 32 + col][0];
        acc = __builtin_amdgcn_mfma_f32_32x32x16_bf16(Af, Bf[ks], acc, 0, 0, 0);
    }

    const int r2e = (int)(ridx[wn] >> 16);
    const float* xcol = x0 + ((size_t)(b * Cn + oh * 32) * Hn + h) * Wn + wn;
    float* ocol = out + ((size_t)(b * Cn + oh * 32) * Hn + h) * Wn + wn;

#pragma unroll
    for (int r = 0; r < 16; ++r) {
        int row = (r & 3) + 8 * (r >> 2) + 4 * kh;     // 0..31 within tile
        int o = oh * 32 + row;
        float xv = xcol[(size_t)row * (Hn * Wn)];      // L2 hit
        float res = acc[r] + bias_lds[o] + xv * att_lds[r2e * 68 + o];
        ocol[(size_t)row * (Hn * Wn)] = res;           // 128B coalesced
    }
}

// ---------------------------------------------------------------------------
extern "C" void kernel_launch(void* const* d_in, const int* in_sizes, int n_in,
                              void* d_out, int out_size, void* d_ws, size_t ws_size,
                              hipStream_t stream)
{
    const float* x0     = (const float*)d_in[0];
    const float* deg    = (const float*)d_in[1];
    const float* q_map  = (const float*)d_in[2];
    const float* w_k1   = (const float*)d_in[3];
    const float* w_k2   = (const float*)d_in[4];
    const float* w_conv = (const float*)d_in[5];
    const float* b_conv = (const float*)d_in[6];
    const float* w_ca1  = (const float*)d_in[7];
    const float* w_ca2  = (const float*)d_in[8];
    const float* w_g1   = (const float*)d_in[9];
    const float* b_g1   = (const float*)d_in[10];
    const float* w_g2   = (const float*)d_in[11];
    const float* b_g2   = (const float*)d_in[12];
    float* outp   = (float*)d_out;
    float* kern_g = (float*)d_ws;                           // 8*3072 floats
    float* att_g  = kern_g + Bn * 3072;                     // 8*256 floats
    unsigned short* wbf = (unsigned short*)(att_g + Bn * 256);  // 4096 bf16

    precomp_kernel<<<Bn + 1, 256, 0, stream>>>(deg, w_k1, w_k2, w_ca1, w_ca2,
                                               w_conv, kern_g, att_g, wbf);
    da_main<<<Bn * Hn, 512, 0, stream>>>(x0, q_map, wbf, b_conv,
                                         w_g1, b_g1, w_g2, b_g2,
                                         kern_g, att_g, outp);
}

// Round 25
// 33.522 us; speedup vs baseline: 1.2586x; 1.2586x over previous
//
#include <hip/hip_runtime.h>
#include <hip/hip_bf16.h>
#include <math.h>

// Problem constants
#define Bn 8
#define Cn 64
#define Hn 128
#define Wn 128
#define Rn 4

typedef __bf16 v8bf __attribute__((ext_vector_type(8)));
typedef float  v16f __attribute__((ext_vector_type(16)));

__device__ __forceinline__ float leaky(float x) { return x >= 0.f ? x : 0.1f * x; }

__device__ __forceinline__ unsigned bf16pair(float a, float b) {
    __hip_bfloat16 ha = __float2bfloat16(a);
    __hip_bfloat16 hb = __float2bfloat16(b);
    return (unsigned)*reinterpret_cast<unsigned short*>(&ha) |
           ((unsigned)*reinterpret_cast<unsigned short*>(&hb) << 16);
}

// VALU wave-wide shifts via DPP (no DS pipe). bound_ctrl -> out-of-range = 0,
// which matches the image border semantics at lanes 0 / 63 exactly.
// (These two have been stable since R20; the quad_perm butterfly from R24 is
// removed after the post-timing divergence.)
__device__ __forceinline__ float dpp_up1(float x) {    // lane n <- lane n-1; lane0 = 0
    int r = __builtin_amdgcn_update_dpp(0, __builtin_bit_cast(int, x),
                                        0x138 /*wave_shr:1*/, 0xf, 0xf, true);
    return __builtin_bit_cast(float, r);
}
__device__ __forceinline__ float dpp_down1(float x) {  // lane n <- lane n+1; lane63 = 0
    int r = __builtin_amdgcn_update_dpp(0, __builtin_bit_cast(int, x),
                                        0x130 /*wave_shl:1*/, 0xf, 0xf, true);
    return __builtin_bit_cast(float, r);
}

// ---------------------------------------------------------------------------
// Kernel A: per-batch dynamic depthwise kernels + channel attn; block Bn
// converts w_conv -> bf16 [o][c].
//   kern_g[b][c][r][12]  (b*3072 + c*48 + r*12 + kk; slots 9..11 pad)
//   att_g [b][r][c]
// ---------------------------------------------------------------------------
__global__ __launch_bounds__(256) void precomp_kernel(
    const float* __restrict__ deg, const float* __restrict__ w_k1,
    const float* __restrict__ w_k2, const float* __restrict__ w_ca1,
    const float* __restrict__ w_ca2, const float* __restrict__ w_conv,
    float* __restrict__ kern_g, float* __restrict__ att_g,
    unsigned short* __restrict__ wbf)
{
    const int tid = threadIdx.x;
    if (blockIdx.x == Bn) {                       // w_conv -> bf16
        for (int f = tid; f < Cn * Cn; f += 256) {
            __hip_bfloat16 hx = __float2bfloat16(w_conv[f]);
            wbf[f] = *reinterpret_cast<unsigned short*>(&hx);
        }
        return;
    }
    const int b = blockIdx.x;
    __shared__ float y_s[64], a_s[64];
    if (tid < 64) {
        float sy = 0.f, sa = 0.f;
#pragma unroll 8
        for (int j = 0; j < 64; ++j) {
            float d = deg[b * 64 + j];
            sy += d * w_k1[tid * 64 + j];
            sa += d * w_ca1[tid * 64 + j];
        }
        y_s[tid] = leaky(sy);
        a_s[tid] = leaky(sa);
    }
    __syncthreads();
    for (int f = tid; f < Cn * Rn * 9; f += 256) {
        int c = f / 36;
        int j = f - c * 36;
        int r = j / 9;
        int kk = j - r * 9;
        int o = c * 9 + kk;
        const float* wp = &w_k2[(r * 576 + o) * 16];
        const float* yp = &y_s[r * 16];
        float s = 0.f;
#pragma unroll
        for (int i = 0; i < 16; ++i) s += yp[i] * wp[i];
        kern_g[b * 3072 + c * 48 + r * 12 + kk] = s;
    }
    {
        int r = tid >> 6, o = tid & 63;
        const float* wp = &w_ca2[(r * 64 + o) * 16];
        const float* ap = &a_s[r * 16];
        float s = 0.f;
#pragma unroll
        for (int i = 0; i < 16; ++i) s += ap[i] * wp[i];
        att_g[b * 256 + tid] = 1.f / (1.f + expf(-s));
    }
}

// ---------------------------------------------------------------------------
// Main kernel: one block per (b,h) row, 512 threads = 8 waves, 3 barriers.
// R20 (col-pair + DPP exchange + 2-deep pipeline) with routing scores
// DISTRIBUTED over all 512 threads (thread (wc = tid>>2, rr = tid&3) scores
// one region: 9 loads + 18 MACs), staged in t_lds scratch (dead until
// phase 1 -> zero LDS growth), then tid<128 does the reference-identical
// serial first-max argmax and publishes ridx. Deterministic (no quad DPP).
// ---------------------------------------------------------------------------
__global__ __launch_bounds__(512) void da_main(
    const float* __restrict__ x0, const float* __restrict__ q_map,
    const unsigned short* __restrict__ wbf, const float* __restrict__ b_conv,
    const float* __restrict__ w_g1, const float* __restrict__ b_g1,
    const float* __restrict__ w_g2, const float* __restrict__ b_g2,
    const float* __restrict__ kern_g, const float* __restrict__ att_g,
    float* __restrict__ out)
{
    __shared__ __align__(16) float kern_lds[Cn * 48];           // 12 KB
    __shared__ __align__(16) unsigned short wc_lds[8][Cn][8];   // 8 KB
    __shared__ __align__(16) unsigned short t_lds[Wn * Cn];     // 16 KB ([w][c], swz)
    __shared__ float att_lds[Rn * 68];                          // 1.1 KB
    __shared__ float bias_lds[Cn];                              // 0.25 KB
    __shared__ unsigned ridx[Wn];                               // 0.5 KB  r1 | r2<<16

    const int tid = threadIdx.x;
    const int ob = blockIdx.x;
    // XCD-aware swizzle: XCD i gets batch i (4 MB image == one L2).
    const int sb = ((ob & 7) << 7) | (ob >> 3);
    const int b = sb >> 7;
    const int h = sb & 127;

    const int lane = tid & 63;
    const int g = tid >> 6;               // wave id: channels [8g, 8g+8)
    const int w0 = 2 * lane;              // this lane's column pair
    const int w1 = w0 + 1;

    // ---- phase 0: staging ----
    for (int f = tid; f < Cn * 48; f += 512)
        kern_lds[f] = kern_g[b * 3072 + f];
    {   // wc subtiles: one conflict-free b128 write per thread
        int cq = tid & 7, o = tid >> 3;
        *(v8bf*)&wc_lds[cq][o][0] = *(const v8bf*)&wbf[o * 64 + cq * 8];
    }
    if (tid < 256) att_lds[(tid >> 6) * 68 + (tid & 63)] = att_g[b * 256 + tid];
    if (tid < 64) bias_lds[tid] = b_conv[tid];

    // routing scores: distributed (col = tid>>2, region = tid&3); staged in
    // t_lds scratch (dead until phase 1). Linear conflict-free writes.
    {
        float* scf = (float*)t_lds;       // 1024 of 4096 float slots
        const int wc = tid >> 2;          // column 0..127
        const int rr = tid & 3;           // region candidate
        float qv[9];
#pragma unroll
        for (int dh = 0; dh < 3; ++dh) {
            int row = h - 1 + dh;
#pragma unroll
            for (int dw = 0; dw < 3; ++dw) {
                int col = wc - 1 + dw;
                qv[dh * 3 + dw] = (row >= 0 && row < Hn && col >= 0 && col < Wn)
                                      ? q_map[(b * Hn + row) * Wn + col] : 0.f;
            }
        }
        float s1 = b_g1[rr], s2 = b_g2[rr];
#pragma unroll
        for (int k = 0; k < 9; ++k) {
            s1 += qv[k] * w_g1[rr * 9 + k];
            s2 += qv[k] * w_g2[rr * 9 + k];
        }
        scf[tid] = s1;
        scf[512 + tid] = s2;
    }
    __syncthreads();

    if (tid < 128) {                      // serial first-max argmax (reference-identical)
        const float* scf = (const float*)t_lds;
        float4 A = *(const float4*)&scf[tid * 4];
        float4 B = *(const float4*)&scf[512 + tid * 4];
        float bb1 = A.x; int r1i = 0;
        if (A.y > bb1) { bb1 = A.y; r1i = 1; }
        if (A.z > bb1) { bb1 = A.z; r1i = 2; }
        if (A.w > bb1) { bb1 = A.w; r1i = 3; }
        float bb2 = B.x; int r2i = 0;
        if (B.y > bb2) { bb2 = B.y; r2i = 1; }
        if (B.z > bb2) { bb2 = B.z; r2i = 2; }
        if (B.w > bb2) { bb2 = B.w; r2i = 3; }
        ridx[tid] = (unsigned)r1i | ((unsigned)r2i << 16);
    }
    __syncthreads();

    // ---- phase 1: column-pair depthwise, 2-deep pipelined, DPP exchange ----
    const bool okm = (h > 0);
    const bool okp = (h < Hn - 1);
    const float* xbase = x0 + (size_t)(b * Cn) * Hn * Wn + h * Wn + w0;
    const int r1a = (int)(ridx[w0] & 0xffffu);
    const int r1b = (int)(ridx[w1] & 0xffffu);
    const int swz = (lane & 7) << 4;      // == ((w0>>1)&7)<<4 == ((w1>>1)&7)<<4

    // two named prefetch buffers (3 x float2 each)
    float2 b0m, b00, b0p;                 // buffer 0
    float2 b1m, b10, b1p;                 // buffer 1

#define LOADC(CI, BM, B0, BP)                                             \
    do {                                                                  \
        const float* xc = xbase + (8 * g + (CI)) * (Hn * Wn);             \
        BM = okm ? *(const float2*)(xc - Wn) : make_float2(0.f, 0.f);     \
        B0 = *(const float2*)xc;                                          \
        BP = okp ? *(const float2*)(xc + Wn) : make_float2(0.f, 0.f);     \
    } while (0)

    float tp0 = 0.f, tp1 = 0.f;           // previous channel's outputs
    LOADC(0, b0m, b00, b0p);
    LOADC(1, b1m, b10, b1p);
#pragma unroll
    for (int ci = 0; ci < 8; ++ci) {
        float2 avm, av0, avp;
        if ((ci & 1) == 0) { avm = b0m; av0 = b00; avp = b0p; }
        else               { avm = b1m; av0 = b10; avp = b1p; }
        if (ci < 6) {                      // refill the freed buffer (static)
            if ((ci & 1) == 0) LOADC(ci + 2, b0m, b00, b0p);
            else               LOADC(ci + 2, b1m, b10, b1p);
        }

        // outer neighbors via VALU DPP wave shifts (lane0/63 auto-zero = border)
        float lm = dpp_up1(avm.y),  l0 = dpp_up1(av0.y),  lp = dpp_up1(avp.y);
        float rm = dpp_down1(avm.x), r0 = dpp_down1(av0.x), rp = dpp_down1(avp.x);

        const int c = 8 * g + ci;
        const float* kpa = &kern_lds[c * 48 + r1a * 12];    // col0 kernel
        float4 a03 = *(const float4*)kpa;
        float4 a47 = *(const float4*)(kpa + 4);
        float a8 = kpa[8];
        float t0 = lm    * a03.x + avm.x * a03.y + avm.y * a03.z
                 + l0    * a03.w + av0.x * a47.x + av0.y * a47.y
                 + lp    * a47.z + avp.x * a47.w + avp.y * a8;
        const float* kpb = &kern_lds[c * 48 + r1b * 12];    // col1 kernel
        float4 b03 = *(const float4*)kpb;
        float4 b47 = *(const float4*)(kpb + 4);
        float b8 = kpb[8];
        float t1 = avm.x * b03.x + avm.y * b03.y + rm    * b03.z
                 + av0.x * b03.w + av0.y * b47.x + r0    * b47.y
                 + avp.x * b47.z + avp.y * b47.w + rp    * b8;
        t0 = leaky(t0);
        t1 = leaky(t1);

        if (ci & 1) {                     // write the completed channel pair
            unsigned q0 = bf16pair(tp0, t0);
            unsigned q1 = bf16pair(tp1, t1);
            const int cbyte = (8 * g + ci - 1) * 2;
            *(unsigned*)((char*)t_lds + w0 * 128 + (cbyte ^ swz)) = q0;
            *(unsigned*)((char*)t_lds + w1 * 128 + (cbyte ^ swz)) = q1;
        } else {
            tp0 = t0;
            tp1 = t1;
        }
    }
#undef LOADC
    __syncthreads();

    // ---- phase 2: MFMA channel mix + fused epilogue (R18 path) ----
    const int v = tid >> 6;               // wave 0..7
    const int wt = v & 3;                 // w-tile (32 cols)
    const int oh = v >> 2;                // o-half (32 rows)
    const int col = lane & 31;
    const int kh = lane >> 5;
    const int wn = wt * 32 + col;         // this lane's output column

    v8bf Bf[4];
#pragma unroll
    for (int ks = 0; ks < 4; ++ks) {
        int cbyte = (16 * ks + 8 * kh) * 2;
        Bf[ks] = *(const v8bf*)((const char*)t_lds + wn * 128 +
                                (cbyte ^ (((wn >> 1) & 7) << 4)));
    }

    v16f acc;
#pragma unroll
    for (int i = 0; i < 16; ++i) acc[i] = 0.f;

#pragma unroll
    for (int ks = 0; ks < 4; ++ks) {
        const int cq = 2 * ks + kh;
        v8bf Af = *(const v8bf*)&wc_lds[cq][oh * 32 + col][0];
        acc = __builtin_amdgcn_mfma_f32_32x32x16_bf16(Af, Bf[ks], acc, 0, 0, 0);
    }

    const int r2e = (int)(ridx[wn] >> 16);
    const float* xcol = x0 + ((size_t)(b * Cn + oh * 32) * Hn + h) * Wn + wn;
    float* ocol = out + ((size_t)(b * Cn + oh * 32) * Hn + h) * Wn + wn;

#pragma unroll
    for (int r = 0; r < 16; ++r) {
        int row = (r & 3) + 8 * (r >> 2) + 4 * kh;     // 0..31 within tile
        int o = oh * 32 + row;
        float xv = xcol[(size_t)row * (Hn * Wn)];      // L2 hit
        float res = acc[r] + bias_lds[o] + xv * att_lds[r2e * 68 + o];
        ocol[(size_t)row * (Hn * Wn)] = res;           // 128B coalesced
    }
}

// ---------------------------------------------------------------------------
extern "C" void kernel_launch(void* const* d_in, const int* in_sizes, int n_in,
                              void* d_out, int out_size, void* d_ws, size_t ws_size,
                              hipStream_t stream)
{
    const float* x0     = (const float*)d_in[0];
    const float* deg    = (const float*)d_in[1];
    const float* q_map  = (const float*)d_in[2];
    const float* w_k1   = (const float*)d_in[3];
    const float* w_k2   = (const float*)d_in[4];
    const float* w_conv = (const float*)d_in[5];
    const float* b_conv = (const float*)d_in[6];
    const float* w_ca1  = (const float*)d_in[7];
    const float* w_ca2  = (const float*)d_in[8];
    const float* w_g1   = (const float*)d_in[9];
    const float* b_g1   = (const float*)d_in[10];
    const float* w_g2   = (const float*)d_in[11];
    const float* b_g2   = (const float*)d_in[12];
    float* outp   = (float*)d_out;
    float* kern_g = (float*)d_ws;                           // 8*3072 floats
    float* att_g  = kern_g + Bn * 3072;                     // 8*256 floats
    unsigned short* wbf = (unsigned short*)(att_g + Bn * 256);  // 4096 bf16

    precomp_kernel<<<Bn + 1, 256, 0, stream>>>(deg, w_k1, w_k2, w_ca1, w_ca2,
                                               w_conv, kern_g, att_g, wbf);
    da_main<<<Bn * Hn, 512, 0, stream>>>(x0, q_map, wbf, b_conv,
                                         w_g1, b_g1, w_g2, b_g2,
                                         kern_g, att_g, outp);
}